// Round 11
// baseline (41.307 us; speedup 1.0000x reference)
//
#include <hip/hip_runtime.h>
#include <hip/hip_bf16.h>

namespace {

// may_alias: LDS is written as u64 (bf16x4 packs) and read as bf16x8.
typedef short bf16x8 __attribute__((ext_vector_type(8), may_alias));
typedef unsigned long long u64_ma __attribute__((may_alias));
typedef __attribute__((ext_vector_type(16))) float f32x16;   // MFMA 32x32 acc

constexpr int kB = 32, kT = 16384, kCin = 32, kCout = 32;
constexpr int kL = 64;             // owned rows per chunk
constexpr int kK = 32;             // zero-state warm-up
constexpr int kChunks = kT / kL;   // 256
constexpr int kWpB = 4;            // waves per block
constexpr int kRS = 80;            // LDS bf16 row stride: 64B data + 16B pad
constexpr int kStageRows = 34;     // 32 rows + 2 halo rows
constexpr int kStageB = kStageRows * kRS;  // 2720 B per wave
constexpr int kNT = 3;             // 1 warm-up tile + 2 owned tiles

__device__ __forceinline__ unsigned bfbits(float f) {
  return (unsigned)__builtin_bit_cast(unsigned short, __float2bfloat16(f));
}

// R8 structure at 32 waves/CU (Little's-law experiment): kL=64 -> 8192 waves,
// 8 blocks/CU. VGPR slimmed <=64 via (1) B-fragments in block-shared LDS,
// (2) per-quad shfl exchange (live 4, not 16), (3) 4-load prefetch + LDS->LDS
// halo copy (next stage's first 2 rows == current stage's last 2 rows).
__global__ __launch_bounds__(256, 8) void mimo_mfma8(
    const float* __restrict__ u,        // [B, T, CIN]
    const float* __restrict__ x0,       // [B, 2, COUT]
    const float* __restrict__ a_coeff,  // [2, COUT]
    const float* __restrict__ b_coeff,  // [3, CIN, COUT]
    float* __restrict__ out)            // [B, T, COUT]
{
  __shared__ char stage[kWpB][kStageB];   // 10.6 KiB
  __shared__ bf16x8 BfL[6][64];           // 6 KiB, block-shared B fragments

  const int tidx = (int)threadIdx.x;
  const int lane = tidx & 63;
  const int col  = lane & 31;          // output channel / time-row within tile
  const int g    = lane >> 5;          // lane-half (k-slot group / C-row +4)
  const int widx = tidx >> 6;
  const int wid  = (int)blockIdx.x * kWpB + widx;   // 0..8191
  const int b     = wid >> 8;          // 0..31
  const int chunk = wid & (kChunks - 1);
  const int t0     = chunk * kL;
  const int tstart = t0 - kK;          // unified: chunk 0 warms over zero-pad

  char* Sw = &stage[widx][0];

  // B fragments into block-shared LDS (wave 0 only; identical for all waves).
  // Slot (g,j) of K-step (tau,h) = b_coeff[2-tau][16g+8h+j][col]; the A-side
  // uses the SAME slot->channel map, so the HW k-order cancels.
  if (widx == 0) {
#pragma unroll
    for (int tau = 0; tau < 3; ++tau)
#pragma unroll
      for (int h = 0; h < 2; ++h) {
        const float* bp = b_coeff + (size_t)(2 - tau) * kCin * kCout
                          + (16 * g + 8 * h) * kCout + col;
        bf16x8 fr;
#pragma unroll
        for (int j = 0; j < 8; ++j)
          fr[j] = (short)__builtin_bit_cast(unsigned short,
                                            __float2bfloat16(bp[j * kCout]));
        BfL[tau * 2 + h][lane] = fr;
      }
  }
  __syncthreads();   // once per kernel

  const float a1 = a_coeff[col];
  const float a2 = a_coeff[kCout + col];
  // chunk-0 exact initial state, injected at tbase == t0 (warm-up over
  // zero-padded u leaves the state at exactly 0 for chunk 0).
  float i1 = 0.f, i2 = 0.f;
  if (chunk == 0) {
    i1 = x0[(b * 2 + 1) * kCout + col];
    i2 = x0[(b * 2 + 0) * kCout + col];
  }
  float s1 = 0.f, s2 = 0.f;

  const float* ub = u + (size_t)b * kT * kCin;
  float* ob = out + (size_t)b * kT * kCout;

  // Coalesced stage load: f4-index f of a stage starting at rowbase.
  auto gload = [&](int rowbase, int f) -> float4 {
    const int grow = rowbase + (f >> 3);
    if (grow >= 0)
      return *(const float4*)(ub + (size_t)grow * kCin + ((f & 7) << 2));
    float4 z; z.x = 0.f; z.y = 0.f; z.z = 0.f; z.w = 0.f;
    return z;
  };
  // cvt f32x4 -> bf16x4 and ds_write_b64 into the 80B-stride stage.
  auto stash = [&](int f, float4 v) {
    const unsigned lo = bfbits(v.x) | (bfbits(v.y) << 16);
    const unsigned hi = bfbits(v.z) | (bfbits(v.w) << 16);
    const unsigned long long q = ((unsigned long long)hi << 32) | lo;
    *(u64_ma*)(Sw + (f >> 3) * kRS + (f & 7) * 8) = q;
  };

  // -------- prologue: stage rows [tstart-2, tstart+32) --------
  {
    const int rowbase = tstart - 2;   // negative rows staged as zeros
    float4 p0 = gload(rowbase, lane);
    float4 p1 = gload(rowbase, lane + 64);
    float4 p2 = gload(rowbase, lane + 128);
    float4 p3 = gload(rowbase, lane + 192);
    float4 p4;
    if (lane < 16) p4 = gload(rowbase, lane + 256);
    stash(lane, p0);
    stash(lane + 64, p1);
    stash(lane + 128, p2);
    stash(lane + 192, p3);
    if (lane < 16) stash(lane + 256, p4);
  }
  asm volatile("" ::: "memory");   // stage writes ordered before tile-0 reads

  for (int tile = 0; tile < kNT; ++tile) {
    const int tbase = tstart + 32 * tile;
    const bool last = (tile + 1 == kNT);

    // issue-early: next stage's 32 NEW rows (tbase+32 .. tbase+63) fly during
    // this tile's compute; the 2 halo rows come from LDS (current slots 32,33).
    float4 n0, n1, n2, n3;
    if (!last) {
      const int rowbase = tbase + 32;
      n0 = gload(rowbase, lane);
      n1 = gload(rowbase, lane + 64);
      n2 = gload(rowbase, lane + 128);
      n3 = gload(rowbase, lane + 192);
    }

    // ---- FIR: 6x ds_read_b128 (A) + 6x ds_read_b128 (B from BfL) + 6 MFMA ----
    f32x16 acc;
#pragma unroll
    for (int i = 0; i < 16; ++i) acc[i] = 0.f;
#pragma unroll
    for (int tau = 0; tau < 3; ++tau) {
      const char* rp = Sw + (col + tau) * kRS + 32 * g;
#pragma unroll
      for (int h = 0; h < 2; ++h) {
        const bf16x8 fa = *(const bf16x8*)(rp + 16 * h);
        const bf16x8 fb = BfL[tau * 2 + h][lane];
        acc = __builtin_amdgcn_mfma_f32_32x32x16_bf16(fa, fb, acc, 0, 0, 0);
      }
    }

    // chunk-0 exact state injection at the first owned tile.
    if (chunk == 0 && tbase == t0) { s1 = i1; s2 = i2; }

    // ---- IIR per reg-quad: 4 shfls live at a time; both halves run the
    // chain redundantly. Reg r (half gg) holds row (r&3) + 8*(r>>2) + 4*gg.
    const bool owned = (tbase >= t0);
    float x1 = s1, x2 = s2;
#pragma unroll
    for (int q = 0; q < 4; ++q) {
      const float o0 = __shfl_xor(acc[4 * q + 0], 32);
      const float o1 = __shfl_xor(acc[4 * q + 1], 32);
      const float o2 = __shfl_xor(acc[4 * q + 2], 32);
      const float o3 = __shfl_xor(acc[4 * q + 3], 32);
      // segment half 0: rows tbase+8q+0..3 (lanes g==0 own/store)
      {
        const float v0 = g ? o0 : acc[4 * q + 0];
        const float v1 = g ? o1 : acc[4 * q + 1];
        const float v2 = g ? o2 : acc[4 * q + 2];
        const float v3 = g ? o3 : acc[4 * q + 3];
        const float y0 = fmaf(a1, x1, fmaf(a2, x2, v0));
        const float y1 = fmaf(a1, y0, fmaf(a2, x1, v1));
        const float y2 = fmaf(a1, y1, fmaf(a2, y0, v2));
        const float y3 = fmaf(a1, y2, fmaf(a2, y1, v3));
        if (owned && g == 0) {
          float* op = ob + (size_t)(tbase + 8 * q) * kCout + col;
          op[0 * kCout] = y0; op[1 * kCout] = y1;
          op[2 * kCout] = y2; op[3 * kCout] = y3;
        }
        x2 = y2; x1 = y3;
      }
      // segment half 1: rows tbase+8q+4..7 (lanes g==1 own/store)
      {
        const float v0 = g ? acc[4 * q + 0] : o0;
        const float v1 = g ? acc[4 * q + 1] : o1;
        const float v2 = g ? acc[4 * q + 2] : o2;
        const float v3 = g ? acc[4 * q + 3] : o3;
        const float y0 = fmaf(a1, x1, fmaf(a2, x2, v0));
        const float y1 = fmaf(a1, y0, fmaf(a2, x1, v1));
        const float y2 = fmaf(a1, y1, fmaf(a2, y0, v2));
        const float y3 = fmaf(a1, y2, fmaf(a2, y1, v3));
        if (owned && g == 1) {
          float* op = ob + (size_t)(tbase + 8 * q + 4) * kCout + col;
          op[0 * kCout] = y0; op[1 * kCout] = y1;
          op[2 * kCout] = y2; op[3 * kCout] = y3;
        }
        x2 = y2; x1 = y3;
      }
    }
    s1 = x1; s2 = x2;

    // write-late refill: halo copy (slots 32,33 -> 0,1) then 32 new rows into
    // slots 2..33. Order pinned by compiler barriers; wave-local LDS FIFO
    // executes DS ops in issue order (reads of 32,33 precede their overwrite).
    if (!last) {
      asm volatile("" ::: "memory");   // this tile's ds_reads issue first
      if (lane < 16) {
        const int r = lane >> 3, cst = (lane & 7) * 8;
        const u64_ma hv = *(const u64_ma*)(Sw + (32 + r) * kRS + cst);
        *(u64_ma*)(Sw + r * kRS + cst) = hv;
      }
      stash(lane + 16, n0);          // f4 slot 16 == row slot 2
      stash(lane + 16 + 64, n1);
      stash(lane + 16 + 128, n2);
      stash(lane + 16 + 192, n3);
      asm volatile("" ::: "memory");   // refill before next tile's ds_reads
    }
  }
}

}  // namespace

extern "C" void kernel_launch(void* const* d_in, const int* in_sizes, int n_in,
                              void* d_out, int out_size, void* d_ws, size_t ws_size,
                              hipStream_t stream) {
  const float* u  = (const float*)d_in[0];
  const float* x0 = (const float*)d_in[1];
  const float* a  = (const float*)d_in[2];
  const float* bb = (const float*)d_in[3];
  float* out = (float*)d_out;

  dim3 grid(kB * kChunks / kWpB);  // 8192 waves / 4 = 2048 blocks -> 8/CU
  dim3 block(256);
  hipLaunchKernelGGL(mimo_mfma8, grid, block, 0, stream, u, x0, a, bb, out);
}

// Round 12
// 40.888 us; speedup vs baseline: 1.0102x; 1.0102x over previous
//
#include <hip/hip_runtime.h>
#include <hip/hip_bf16.h>

namespace {

// may_alias: LDS is written as u64 (bf16x4 packs) and read as bf16x8.
typedef short bf16x8 __attribute__((ext_vector_type(8), may_alias));
typedef unsigned long long u64_ma __attribute__((may_alias));
typedef __attribute__((ext_vector_type(16))) float f32x16;   // MFMA 32x32 acc

constexpr int kB = 32, kT = 16384, kCin = 32, kCout = 32;
constexpr int kL = 128;            // owned rows per chunk
constexpr int kK = 32;             // zero-state warm-up
constexpr int kChunks = kT / kL;   // 128
constexpr int kWpB = 4;            // waves per block
constexpr int kRS = 80;            // LDS bf16 row stride: 64B data + 16B pad
                                   // (bank start = 20*row mod 32, period 8 ->
                                   //  uniform 4-way b128 floor)
constexpr int kStageRows = 34;     // 32 rows + 2 halo rows
constexpr int kStageB = kStageRows * kRS;  // 2720 B per stage
constexpr int kNT = 5;             // 1 warm-up tile + 4 owned tiles

__device__ __forceinline__ unsigned bfbits(float f) {
  return (unsigned)__builtin_bit_cast(unsigned short, __float2bfloat16(f));
}

// R8's proven kernel + DEPTH-2 prefetch via double-buffered wave-local LDS
// stage: iteration k issues tile k+2's loads, computes tile k, stashes tile
// k+1 (loaded one full compute phase ago -> its burst has drained).
__global__ __launch_bounds__(256, 4) void mimo_mfma9(
    const float* __restrict__ u,        // [B, T, CIN]
    const float* __restrict__ x0,       // [B, 2, COUT]
    const float* __restrict__ a_coeff,  // [2, COUT]
    const float* __restrict__ b_coeff,  // [3, CIN, COUT]
    float* __restrict__ out)            // [B, T, COUT]
{
  __shared__ char stage[kWpB][2][kStageB];   // 21.25 KiB per block

  const int tidx = (int)threadIdx.x;
  const int lane = tidx & 63;
  const int col  = lane & 31;          // output channel / time-row within tile
  const int g    = lane >> 5;          // lane-half (k-slot group / C-row +4)
  const int widx = tidx >> 6;
  const int wid  = (int)blockIdx.x * kWpB + widx;
  const int b     = wid >> 7;          // 0..31
  const int chunk = wid & (kChunks - 1);
  const int t0     = chunk * kL;
  const int tstart = t0 - kK;          // unified: chunk 0 warms over zero-pad

  // B fragments: slot (g,j) of K-step (tau,h) = b_coeff[2-tau][16g+8h+j][col].
  // A uses the SAME slot->channel map, so the HW k-order cancels.
  bf16x8 Bf[3][2];
#pragma unroll
  for (int tau = 0; tau < 3; ++tau)
#pragma unroll
    for (int h = 0; h < 2; ++h) {
      const float* bp = b_coeff + (size_t)(2 - tau) * kCin * kCout
                        + (16 * g + 8 * h) * kCout + col;
      bf16x8 fr;
#pragma unroll
      for (int j = 0; j < 8; ++j)
        fr[j] = (short)__builtin_bit_cast(unsigned short, __float2bfloat16(bp[j * kCout]));
      Bf[tau][h] = fr;
    }

  const float a1 = a_coeff[col];
  const float a2 = a_coeff[kCout + col];
  // chunk-0 exact initial state, injected at tbase == t0 (warm-up over
  // zero-padded u leaves the state at exactly 0 for chunk 0).
  float i1 = 0.f, i2 = 0.f;
  if (chunk == 0) {
    i1 = x0[(b * 2 + 1) * kCout + col];
    i2 = x0[(b * 2 + 0) * kCout + col];
  }
  float s1 = 0.f, s2 = 0.f;

  const float* ub = u + (size_t)b * kT * kCin;
  float* ob = out + (size_t)b * kT * kCout;

  // Coalesced stage load: f4-index f of a 34-row stage starting at rowbase.
  auto gload = [&](int rowbase, int f) -> float4 {
    const int grow = rowbase + (f >> 3);
    if (grow >= 0)
      return *(const float4*)(ub + (size_t)grow * kCin + ((f & 7) << 2));
    float4 z; z.x = 0.f; z.y = 0.f; z.z = 0.f; z.w = 0.f;
    return z;
  };
  // cvt f32x4 -> bf16x4 and ds_write_b64 into an 80B-stride stage buffer.
  auto stash = [&](char* S, int f, float4 v) {
    const unsigned lo = bfbits(v.x) | (bfbits(v.y) << 16);
    const unsigned hi = bfbits(v.z) | (bfbits(v.w) << 16);
    const unsigned long long q = ((unsigned long long)hi << 32) | lo;
    *(u64_ma*)(S + (f >> 3) * kRS + (f & 7) * 8) = q;
  };

  // -------- prologue --------
  // Stage tile 0 into buf0 (rows tstart-2 .. tstart+31; negative rows = 0).
  {
    char* S0 = &stage[widx][0][0];
    const int rowbase = tstart - 2;
    float4 p0 = gload(rowbase, lane);
    float4 p1 = gload(rowbase, lane + 64);
    float4 p2 = gload(rowbase, lane + 128);
    float4 p3 = gload(rowbase, lane + 192);
    float4 p4;
    if (lane < 16) p4 = gload(rowbase, lane + 256);
    stash(S0, lane, p0);
    stash(S0, lane + 64, p1);
    stash(S0, lane + 128, p2);
    stash(S0, lane + 192, p3);
    if (lane < 16) stash(S0, lane + 256, p4);
  }
  asm volatile("" ::: "memory");
  // Prefetch tile 1's rows into registers (depth-1 of the 2-deep pipe).
  float4 c0, c1, c2, c3, c4;
  {
    const int rowbase = tstart + 30;
    c0 = gload(rowbase, lane);
    c1 = gload(rowbase, lane + 64);
    c2 = gload(rowbase, lane + 128);
    c3 = gload(rowbase, lane + 192);
    if (lane < 16) c4 = gload(rowbase, lane + 256);
  }

#pragma unroll
  for (int tile = 0; tile < kNT; ++tile) {
    char* Scur = &stage[widx][tile & 1][0];
    char* Snxt = &stage[widx][(tile + 1) & 1][0];
    const int tbase = tstart + 32 * tile;

    // depth-2: issue tile+2's loads now; they drain during TWO compute phases.
    float4 n0, n1, n2, n3, n4;
    if (tile + 2 < kNT) {
      const int rowbase = tbase + 62;   // (tstart + 32*(tile+2)) - 2
      n0 = gload(rowbase, lane);
      n1 = gload(rowbase, lane + 64);
      n2 = gload(rowbase, lane + 128);
      n3 = gload(rowbase, lane + 192);
      if (lane < 16) n4 = gload(rowbase, lane + 256);
    }

    // ---- FIR: 6x ds_read_b128 (bf16 direct) + 6 MFMAs ----
    f32x16 acc;
#pragma unroll
    for (int i = 0; i < 16; ++i) acc[i] = 0.f;
#pragma unroll
    for (int tau = 0; tau < 3; ++tau) {
      const char* rp = Scur + (col + tau) * kRS + 32 * g;
#pragma unroll
      for (int h = 0; h < 2; ++h) {
        const bf16x8 fa = *(const bf16x8*)(rp + 16 * h);
        acc = __builtin_amdgcn_mfma_f32_32x32x16_bf16(fa, Bf[tau][h], acc, 0, 0, 0);
      }
    }

    // chunk-0 exact state injection at the first owned tile.
    if (chunk == 0 && tbase == t0) { s1 = i1; s2 = i2; }

    // ---- IIR per reg-quad (R11-proven): 4 shfls live at a time; both
    // halves run the chain redundantly. Reg r (half gg) holds row
    // (r&3) + 8*(r>>2) + 4*gg.
    const bool owned = (tbase >= t0);
    float x1 = s1, x2 = s2;
#pragma unroll
    for (int q = 0; q < 4; ++q) {
      const float o0 = __shfl_xor(acc[4 * q + 0], 32);
      const float o1 = __shfl_xor(acc[4 * q + 1], 32);
      const float o2 = __shfl_xor(acc[4 * q + 2], 32);
      const float o3 = __shfl_xor(acc[4 * q + 3], 32);
      // segment half 0: rows tbase+8q+0..3 (lanes g==0 own/store)
      {
        const float v0 = g ? o0 : acc[4 * q + 0];
        const float v1 = g ? o1 : acc[4 * q + 1];
        const float v2 = g ? o2 : acc[4 * q + 2];
        const float v3 = g ? o3 : acc[4 * q + 3];
        const float y0 = fmaf(a1, x1, fmaf(a2, x2, v0));
        const float y1 = fmaf(a1, y0, fmaf(a2, x1, v1));
        const float y2 = fmaf(a1, y1, fmaf(a2, y0, v2));
        const float y3 = fmaf(a1, y2, fmaf(a2, y1, v3));
        if (owned && g == 0) {
          float* op = ob + (size_t)(tbase + 8 * q) * kCout + col;
          op[0 * kCout] = y0; op[1 * kCout] = y1;
          op[2 * kCout] = y2; op[3 * kCout] = y3;
        }
        x2 = y2; x1 = y3;
      }
      // segment half 1: rows tbase+8q+4..7 (lanes g==1 own/store)
      {
        const float v0 = g ? acc[4 * q + 0] : o0;
        const float v1 = g ? acc[4 * q + 1] : o1;
        const float v2 = g ? acc[4 * q + 2] : o2;
        const float v3 = g ? acc[4 * q + 3] : o3;
        const float y0 = fmaf(a1, x1, fmaf(a2, x2, v0));
        const float y1 = fmaf(a1, y0, fmaf(a2, x1, v1));
        const float y2 = fmaf(a1, y1, fmaf(a2, y0, v2));
        const float y3 = fmaf(a1, y2, fmaf(a2, y1, v3));
        if (owned && g == 1) {
          float* op = ob + (size_t)(tbase + 8 * q + 4) * kCout + col;
          op[0 * kCout] = y0; op[1 * kCout] = y1;
          op[2 * kCout] = y2; op[3 * kCout] = y3;
        }
        x2 = y2; x1 = y3;
      }
    }
    s1 = x1; s2 = x2;

    // Stash tile+1 (registers loaded one full iteration ago, burst drained)
    // into the other buffer; rotate the prefetch registers.
    if (tile + 1 < kNT) {
      asm volatile("" ::: "memory");   // this tile's ds_reads issue first
      stash(Snxt, lane, c0);
      stash(Snxt, lane + 64, c1);
      stash(Snxt, lane + 128, c2);
      stash(Snxt, lane + 192, c3);
      if (lane < 16) stash(Snxt, lane + 256, c4);
      asm volatile("" ::: "memory");   // stash before next tile's ds_reads
      c0 = n0; c1 = n1; c2 = n2; c3 = n3; c4 = n4;
    }
  }
}

}  // namespace

extern "C" void kernel_launch(void* const* d_in, const int* in_sizes, int n_in,
                              void* d_out, int out_size, void* d_ws, size_t ws_size,
                              hipStream_t stream) {
  const float* u  = (const float*)d_in[0];
  const float* x0 = (const float*)d_in[1];
  const float* a  = (const float*)d_in[2];
  const float* bb = (const float*)d_in[3];
  float* out = (float*)d_out;

  dim3 grid(kB * kChunks / kWpB);  // 4096 waves / 4 = 1024 blocks
  dim3 block(256);
  hipLaunchKernelGGL(mimo_mfma9, grid, block, 0, stream, u, x0, a, bb, out);
}

// Round 13
// 29.439 us; speedup vs baseline: 1.4031x; 1.3889x over previous
//
#include <hip/hip_runtime.h>
#include <hip/hip_bf16.h>

namespace {

// may_alias everywhere LDS/out is accessed through more than one type.
typedef short bf16x8 __attribute__((ext_vector_type(8), may_alias));
typedef unsigned long long u64_ma __attribute__((may_alias));
typedef float f32x4_ma __attribute__((ext_vector_type(4), may_alias));
typedef __attribute__((ext_vector_type(16))) float f32x16;   // MFMA 32x32 acc

constexpr int kB = 32, kT = 16384, kCin = 32, kCout = 32;
constexpr int kL = 128;            // owned rows per chunk
constexpr int kK = 32;             // zero-state warm-up
constexpr int kChunks = kT / kL;   // 128
constexpr int kWpB = 4;            // waves per block
constexpr int kRS = 80;            // LDS bf16 row stride: 64B data + 16B pad
constexpr int kStageRows = 34;     // 32 rows + 2 halo rows
constexpr int kStageB = kStageRows * kRS;  // 2720 B per stage
constexpr int kNT = 5;             // 1 warm-up tile + 4 owned tiles
constexpr int kTS = 36;            // transpose-buffer row stride (floats):
                                   // 144B, 16B-aligned; write pattern 2-way
                                   // (free, m136), reads 16B-aligned
constexpr int kTBufB = 32 * kTS * 4;       // 4608 B per wave

__device__ __forceinline__ unsigned bfbits(float f) {
  return (unsigned)__builtin_bit_cast(unsigned short, __float2bfloat16(f));
}

// R8's proven kernel with a rebuilt store path: IIR results go to a wave-local
// LDS transpose buffer; each owned tile is then emitted as 4 full-wave
// global_store_dwordx4 (4x 1KB contiguous) instead of 32 half-masked dword
// stores. Tests the write-amplification theory (R1/R2/R11/R12 WRITE ledger).
__global__ __launch_bounds__(256, 4) void mimo_mfma10(
    const float* __restrict__ u,        // [B, T, CIN]
    const float* __restrict__ x0,       // [B, 2, COUT]
    const float* __restrict__ a_coeff,  // [2, COUT]
    const float* __restrict__ b_coeff,  // [3, CIN, COUT]
    float* __restrict__ out)            // [B, T, COUT]
{
  __shared__ char stage[kWpB][kStageB];   // 10.6 KiB
  __shared__ char tbuf[kWpB][kTBufB];     // 18.0 KiB

  const int tidx = (int)threadIdx.x;
  const int lane = tidx & 63;
  const int col  = lane & 31;          // output channel / time-row within tile
  const int g    = lane >> 5;          // lane-half (k-slot group / C-row +4)
  const int widx = tidx >> 6;
  const int wid  = (int)blockIdx.x * kWpB + widx;
  const int b     = wid >> 7;          // 0..31
  const int chunk = wid & (kChunks - 1);
  const int t0     = chunk * kL;
  const int tstart = t0 - kK;          // unified: chunk 0 warms over zero-pad

  char* Sw = &stage[widx][0];
  float* Tw = (float*)&tbuf[widx][0];

  // B fragments: slot (g,j) of K-step (tau,h) = b_coeff[2-tau][16g+8h+j][col].
  // A uses the SAME slot->channel map, so the HW k-order cancels.
  bf16x8 Bf[3][2];
#pragma unroll
  for (int tau = 0; tau < 3; ++tau)
#pragma unroll
    for (int h = 0; h < 2; ++h) {
      const float* bp = b_coeff + (size_t)(2 - tau) * kCin * kCout
                        + (16 * g + 8 * h) * kCout + col;
      bf16x8 fr;
#pragma unroll
      for (int j = 0; j < 8; ++j)
        fr[j] = (short)__builtin_bit_cast(unsigned short, __float2bfloat16(bp[j * kCout]));
      Bf[tau][h] = fr;
    }

  const float a1 = a_coeff[col];
  const float a2 = a_coeff[kCout + col];
  // chunk-0 exact initial state, injected at tbase == t0 (warm-up over
  // zero-padded u leaves the state at exactly 0 for chunk 0).
  float i1 = 0.f, i2 = 0.f;
  if (chunk == 0) {
    i1 = x0[(b * 2 + 1) * kCout + col];
    i2 = x0[(b * 2 + 0) * kCout + col];
  }
  float s1 = 0.f, s2 = 0.f;

  const float* ub = u + (size_t)b * kT * kCin;
  float* ob = out + (size_t)b * kT * kCout;

  // Coalesced stage load: f4-index f of a 34-row stage starting at rowbase.
  auto gload = [&](int rowbase, int f) -> float4 {
    const int grow = rowbase + (f >> 3);
    if (grow >= 0)
      return *(const float4*)(ub + (size_t)grow * kCin + ((f & 7) << 2));
    float4 z; z.x = 0.f; z.y = 0.f; z.z = 0.f; z.w = 0.f;
    return z;
  };
  // cvt f32x4 -> bf16x4 and ds_write_b64 into the 80B-stride stage.
  auto stash = [&](int f, float4 v) {
    const unsigned lo = bfbits(v.x) | (bfbits(v.y) << 16);
    const unsigned hi = bfbits(v.z) | (bfbits(v.w) << 16);
    const unsigned long long q = ((unsigned long long)hi << 32) | lo;
    *(u64_ma*)(Sw + (f >> 3) * kRS + (f & 7) * 8) = q;
  };

  // -------- prologue: stage rows [tstart-2, tstart+32) --------
  {
    const int rowbase = tstart - 2;   // negative rows staged as zeros
    float4 p0 = gload(rowbase, lane);
    float4 p1 = gload(rowbase, lane + 64);
    float4 p2 = gload(rowbase, lane + 128);
    float4 p3 = gload(rowbase, lane + 192);
    float4 p4;
    if (lane < 16) p4 = gload(rowbase, lane + 256);
    stash(lane, p0);
    stash(lane + 64, p1);
    stash(lane + 128, p2);
    stash(lane + 192, p3);
    if (lane < 16) stash(lane + 256, p4);
  }
  asm volatile("" ::: "memory");   // stage writes ordered before tile-0 reads

#pragma unroll
  for (int tile = 0; tile < kNT; ++tile) {
    const int tbase = tstart + 32 * tile;
    const bool last = (tile + 1 == kNT);
    const bool owned = (tile >= 1);      // tile 0 is the warm-up tile

    // issue-early: next stage's coalesced global loads fly during compute.
    float4 n0, n1, n2, n3, n4;
    if (!last) {
      const int rowbase = tbase + 30;   // (tbase+32) - 2
      n0 = gload(rowbase, lane);
      n1 = gload(rowbase, lane + 64);
      n2 = gload(rowbase, lane + 128);
      n3 = gload(rowbase, lane + 192);
      if (lane < 16) n4 = gload(rowbase, lane + 256);
    }

    // ---- FIR: 6x ds_read_b128 (bf16 direct) + 6 MFMAs ----
    f32x16 acc;
#pragma unroll
    for (int i = 0; i < 16; ++i) acc[i] = 0.f;
#pragma unroll
    for (int tau = 0; tau < 3; ++tau) {
      const char* rp = Sw + (col + tau) * kRS + 32 * g;
#pragma unroll
      for (int h = 0; h < 2; ++h) {
        const bf16x8 fa = *(const bf16x8*)(rp + 16 * h);
        acc = __builtin_amdgcn_mfma_f32_32x32x16_bf16(fa, Bf[tau][h], acc, 0, 0, 0);
      }
    }

    // chunk-0 exact state injection at the first owned tile.
    if (chunk == 0 && tile == 1) { s1 = i1; s2 = i2; }

    // ---- IIR per reg-quad (R11-proven chain); results go to the LDS
    // transpose buffer instead of masked global stores. Both redundant
    // halves' values are used: lane (col,g) writes rows 8q+4g+0..3.
    // Reg r (half gg) holds row (r&3) + 8*(r>>2) + 4*gg of the tile.
    float x1 = s1, x2 = s2;
#pragma unroll
    for (int q = 0; q < 4; ++q) {
      const float o0 = __shfl_xor(acc[4 * q + 0], 32);
      const float o1 = __shfl_xor(acc[4 * q + 1], 32);
      const float o2 = __shfl_xor(acc[4 * q + 2], 32);
      const float o3 = __shfl_xor(acc[4 * q + 3], 32);
      // rows 8q+0..3 (values identical in both halves)
      const float va0 = g ? o0 : acc[4 * q + 0];
      const float va1 = g ? o1 : acc[4 * q + 1];
      const float va2 = g ? o2 : acc[4 * q + 2];
      const float va3 = g ? o3 : acc[4 * q + 3];
      const float ya0 = fmaf(a1, x1,  fmaf(a2, x2,  va0));
      const float ya1 = fmaf(a1, ya0, fmaf(a2, x1,  va1));
      const float ya2 = fmaf(a1, ya1, fmaf(a2, ya0, va2));
      const float ya3 = fmaf(a1, ya2, fmaf(a2, ya1, va3));
      // rows 8q+4..7
      const float vb0 = g ? acc[4 * q + 0] : o0;
      const float vb1 = g ? acc[4 * q + 1] : o1;
      const float vb2 = g ? acc[4 * q + 2] : o2;
      const float vb3 = g ? acc[4 * q + 3] : o3;
      const float yb0 = fmaf(a1, ya3, fmaf(a2, ya2, vb0));
      const float yb1 = fmaf(a1, yb0, fmaf(a2, ya3, vb1));
      const float yb2 = fmaf(a1, yb1, fmaf(a2, yb0, vb2));
      const float yb3 = fmaf(a1, yb2, fmaf(a2, yb1, vb3));
      x2 = yb2; x1 = yb3;
      if (owned) {
        // full-wave ds_write_b32 x4: lane half g writes rows 8q+4g+i.
        // Banks: (4*row + col) % 32 -> each instr hits every bank twice
        // (2-way = free, m136).
        const int rb = 8 * q + 4 * g;
        Tw[(rb + 0) * kTS + col] = g ? yb0 : ya0;
        Tw[(rb + 1) * kTS + col] = g ? yb1 : ya1;
        Tw[(rb + 2) * kTS + col] = g ? yb2 : ya2;
        Tw[(rb + 3) * kTS + col] = g ? yb3 : ya3;
      }
    }
    s1 = x1; s2 = x2;

    // ---- emit the tile: 4x ds_read_b128 + 4x global_store_dwordx4 ----
    // Each store instr: 64 lanes x 16B = 1KB contiguous, 4KB back-to-back
    // per tile -> clean full-granule HBM writes, no exec-mask churn.
    if (owned) {
      asm volatile("" ::: "memory");   // transpose writes before reads
#pragma unroll
      for (int p = 0; p < 4; ++p) {
        const f32x4_ma v = *(const f32x4_ma*)
            ((const char*)Tw + (8 * p + (lane >> 3)) * (kTS * 4) + (lane & 7) * 16);
        *(f32x4_ma*)(ob + (size_t)(tbase + 8 * p) * kCout + lane * 4) = v;
      }
      asm volatile("" ::: "memory");   // reads before next tile's writes
    }

    // write-late stage refill (wave-local, in-order DS).
    if (!last) {
      asm volatile("" ::: "memory");   // this tile's ds_reads issue first
      stash(lane, n0);
      stash(lane + 64, n1);
      stash(lane + 128, n2);
      stash(lane + 192, n3);
      if (lane < 16) stash(lane + 256, n4);
      asm volatile("" ::: "memory");   // refill before next tile's ds_reads
    }
  }
}

}  // namespace

extern "C" void kernel_launch(void* const* d_in, const int* in_sizes, int n_in,
                              void* d_out, int out_size, void* d_ws, size_t ws_size,
                              hipStream_t stream) {
  const float* u  = (const float*)d_in[0];
  const float* x0 = (const float*)d_in[1];
  const float* a  = (const float*)d_in[2];
  const float* bb = (const float*)d_in[3];
  float* out = (float*)d_out;

  dim3 grid(kB * kChunks / kWpB);  // 4096 waves / 4 = 1024 blocks
  dim3 block(256);
  hipLaunchKernelGGL(mimo_mfma10, grid, block, 0, stream, u, x0, a, bb, out);
}